// Round 1
// baseline (543.575 us; speedup 1.0000x reference)
//
#include <hip/hip_runtime.h>

// CompGraphConv, algebraically restructured:
//   comp_edge[v] = (SO[v] - cntO[v]*x[v]) @ W_O^T + cntO[v]*b_O
//               +  (SI[v] - cntI[v]*x[v]) @ W_I^T + cntI[v]*b_I
//   where SO[v] = sum of x[src] over first-half edges with dst==v (SI: second half).
// Edge kernel scatters only x[src] (64 fp32 atomics/edge) + a count.
// Node kernel does 3 fused GEMVs (W_S, W_O, W_I) with W^T in padded LDS.

#define DF 64

__device__ __forceinline__ float lane_bcast(float v, int k) {
    return __builtin_bit_cast(float, __builtin_amdgcn_readlane(__builtin_bit_cast(int, v), k));
}

__global__ __launch_bounds__(256) void edge_scatter(
        const float* __restrict__ x,
        const int* __restrict__ src,
        const int* __restrict__ dst,
        float* __restrict__ accO, float* __restrict__ accI,
        float* __restrict__ cntO, float* __restrict__ cntI,
        int E, int half) {
    int t = blockIdx.x * 256 + threadIdx.x;
    int e = t >> 6;
    int lane = t & 63;
    if (e >= E) return;
    int s = src[e];
    int d = dst[e];
    float v = x[(size_t)s * DF + lane];
    float* acc = (e < half) ? accO : accI;
    atomicAdd(&acc[(size_t)d * DF + lane], v);
    if (lane == 0) {
        float* cnt = (e < half) ? cntO : cntI;
        atomicAdd(&cnt[d], 1.0f);
    }
}

__global__ __launch_bounds__(256) void node_transform(
        const float* __restrict__ x, const float* __restrict__ r,
        const float* __restrict__ accO, const float* __restrict__ accI,
        const float* __restrict__ cntO, const float* __restrict__ cntI,
        const float* __restrict__ W_O, const float* __restrict__ b_O,
        const float* __restrict__ W_I, const float* __restrict__ b_I,
        const float* __restrict__ W_S, const float* __restrict__ b_S,
        float* __restrict__ out, int N) {
    // W^T staged with +1-pad rows: wt[k*65 + j] = W[j][k]
    __shared__ float wts[64 * 65];
    __shared__ float wto[64 * 65];
    __shared__ float wti[64 * 65];
    for (int i = threadIdx.x; i < 4096; i += 256) {
        int j = i >> 6, k = i & 63;
        wts[k * 65 + j] = W_S[i];
        wto[k * 65 + j] = W_O[i];
        wti[k * 65 + j] = W_I[i];
    }
    __syncthreads();

    const int lane = threadIdx.x & 63;
    const int wave = threadIdx.x >> 6;
    const float bs = b_S[lane], bo = b_O[lane], bi = b_I[lane];
    const float rv = r[lane];

    for (int base = blockIdx.x * 16; base < N; base += gridDim.x * 16) {
        const int v0 = base + wave * 4;   // this wave's 4 nodes
        float xs[4], aO[4], aI[4], acc[4];
        bool valid[4];
        #pragma unroll
        for (int i = 0; i < 4; i++) {
            int v = v0 + i;
            valid[i] = (v < N);
            int vc = valid[i] ? v : (N - 1);
            float xv = x[(size_t)vc * DF + lane];
            float cO = cntO[vc], cI = cntI[vc];
            xs[i] = xv - rv;
            aO[i] = accO[(size_t)vc * DF + lane] - cO * xv;
            aI[i] = accI[(size_t)vc * DF + lane] - cI * xv;
            acc[i] = bs + cO * bo + cI * bi;
        }
        #pragma unroll 16
        for (int k = 0; k < 64; k++) {
            float ws = wts[k * 65 + lane];
            float wo = wto[k * 65 + lane];
            float wi = wti[k * 65 + lane];
            #pragma unroll
            for (int i = 0; i < 4; i++) {
                acc[i] += lane_bcast(xs[i], k) * ws
                        + lane_bcast(aO[i], k) * wo
                        + lane_bcast(aI[i], k) * wi;
            }
        }
        #pragma unroll
        for (int i = 0; i < 4; i++) {
            if (valid[i]) out[(size_t)(v0 + i) * DF + lane] = acc[i];
        }
    }
}

__global__ void r_transform(const float* __restrict__ r,
                            const float* __restrict__ W_R,
                            const float* __restrict__ b_R,
                            float* __restrict__ out, int N) {
    int j = threadIdx.x;  // 64 threads
    float s = b_R[j];
    #pragma unroll 16
    for (int k = 0; k < 64; k++) s += r[k] * W_R[j * 64 + k];
    out[(size_t)N * DF + j] = s;
}

extern "C" void kernel_launch(void* const* d_in, const int* in_sizes, int n_in,
                              void* d_out, int out_size, void* d_ws, size_t ws_size,
                              hipStream_t stream) {
    const float* x   = (const float*)d_in[0];
    const float* r   = (const float*)d_in[1];
    const int*   src = (const int*)d_in[2];
    const int*   dst = (const int*)d_in[3];
    const float* W_O = (const float*)d_in[4];
    const float* b_O = (const float*)d_in[5];
    const float* W_I = (const float*)d_in[6];
    const float* b_I = (const float*)d_in[7];
    const float* W_S = (const float*)d_in[8];
    const float* b_S = (const float*)d_in[9];
    const float* W_R = (const float*)d_in[10];
    const float* b_R = (const float*)d_in[11];
    float* out = (float*)d_out;

    const int N = in_sizes[0] / DF;
    const int E = in_sizes[2];
    const int half = E / 2;

    // ws layout: accO[N*64] | accI[N*64] | cntO[N] | cntI[N]  (~52 MB)
    float* accO = (float*)d_ws;
    float* accI = accO + (size_t)N * DF;
    float* cntO = accI + (size_t)N * DF;
    float* cntI = cntO + N;
    size_t zero_bytes = ((size_t)N * (2 * DF + 2)) * sizeof(float);
    hipMemsetAsync(d_ws, 0, zero_bytes, stream);

    int edge_threads = E * DF;                     // 76.8M, fits int32
    int edge_blocks = (edge_threads + 255) / 256;  // one wave per edge
    edge_scatter<<<edge_blocks, 256, 0, stream>>>(x, src, dst, accO, accI,
                                                  cntO, cntI, E, half);

    node_transform<<<2048, 256, 0, stream>>>(x, r, accO, accI, cntO, cntI,
                                             W_O, b_O, W_I, b_I, W_S, b_S,
                                             out, N);

    r_transform<<<1, 64, 0, stream>>>(r, W_R, b_R, out, N);
}